// Round 1
// baseline (705.200 us; speedup 1.0000x reference)
//
#include <hip/hip_runtime.h>

#define DEVI __device__ __forceinline__

typedef unsigned short u16;
typedef unsigned int u32;
typedef float f32x4 __attribute__((ext_vector_type(4)));
typedef __bf16 bf16x8 __attribute__((ext_vector_type(8)));
typedef unsigned short u16x4 __attribute__((ext_vector_type(4)));
typedef unsigned short u16x8 __attribute__((ext_vector_type(8)));
typedef int i32x4 __attribute__((ext_vector_type(4)));

constexpr int BATCH = 2;
constexpr int T     = 2048;
constexpr int DIM   = 2048;
constexpr int NH    = 16;
constexpr int KVH   = 4;
constexpr int HD    = 128;
constexpr int NQKV  = DIM + 2 * KVH * HD;   // 3072 (q | k | v columns)
constexpr int ROWS  = BATCH * T;            // 4096
constexpr float SCALE = 0.08838834764831845f; // 1/sqrt(HD)

DEVI u16 f2b(float f) {            // fp32 -> bf16 bits, round-nearest-even
  u32 u = __float_as_uint(f);
  return (u16)((u + 0x7fffu + ((u >> 16) & 1u)) >> 16);
}
DEVI float b2f(u16 u) { return __uint_as_float(((u32)u) << 16); }

DEVI f32x4 mfma16(bf16x8 a, bf16x8 b, f32x4 c) {
  return __builtin_amdgcn_mfma_f32_16x16x32_bf16(a, b, c, 0, 0, 0);
}
DEVI void gload16(const void* g, void* l) {  // async global->LDS, 16B/lane
  __builtin_amdgcn_global_load_lds((const __attribute__((address_space(1))) void*)g,
                                   (__attribute__((address_space(3))) void*)l, 16, 0, 0);
}

// ---------------- prep kernels ----------------
__global__ void cvt_bf16_kernel(const float* __restrict__ in, u16* __restrict__ out, int n4) {
  int i = blockIdx.x * 256 + threadIdx.x;
  if (i >= n4) return;
  float4 v = *((const float4*)in + i);
  u16x4 o = { f2b(v.x), f2b(v.y), f2b(v.z), f2b(v.w) };
  *((u16x4*)out + i) = o;
}

__global__ void cs_kernel(const float* __restrict__ c, const float* __restrict__ s,
                          float* __restrict__ cs, int n) {
  int i = blockIdx.x * 256 + threadIdx.x;
  if (i < n) cs[i] = c[i] + s[i];
}

// ---------------- GEMM: C = A @ W^T (+bias), A MxK, W NxK, bf16 in, fp32 acc --------
// 128x128 tile, BK=64, 4 waves (2x2 of 64x64), 16x16x32 MFMA.
// LDS XOR-swizzle (16B granule, row&7) applied via pre-swizzled GLOBAL source
// (global_load_lds writes linearly) and swizzled ds_read addresses.
template<bool BF16OUT, bool BIAS>
__global__ __launch_bounds__(256) void gemm_bt_kernel(
    const u16* __restrict__ A, const u16* __restrict__ W,
    void* __restrict__ Cout, const float* __restrict__ bias,
    int M, int N, int K)
{
  constexpr int BK = 64;
  __shared__ u16 sA[128 * BK];
  __shared__ u16 sB[128 * BK];
  const int nbx = N >> 7;
  const int bx = blockIdx.x % nbx;
  const int by = blockIdx.x / nbx;
  const int m0 = by << 7, n0 = bx << 7;
  const int tid = threadIdx.x;
  const int w = tid >> 6, lane = tid & 63;
  const int wr = w >> 1, wc = w & 1;
  const int lq = lane & 15, lg = lane >> 4;

  f32x4 acc[4][4] = {};

  int srow[4], scb[4];
#pragma unroll
  for (int c = 0; c < 4; ++c) {
    int off = (w * 4 + c) * 1024 + lane * 16;       // byte offset in 16KB tile
    srow[c] = off >> 7;                             // 128B per row (64 bf16)
    scb[c]  = (off & 127) ^ ((srow[c] & 7) << 4);   // pre-swizzled source col-byte
  }

  for (int kt = 0; kt < K; kt += BK) {
#pragma unroll
    for (int c = 0; c < 4; ++c) {
      u16* la = sA + (w * 4 + c) * 512;             // wave-uniform LDS dest
      u16* lb = sB + (w * 4 + c) * 512;
      gload16(A + (size_t)(m0 + srow[c]) * K + kt + (scb[c] >> 1), la);
      gload16(W + (size_t)(n0 + srow[c]) * K + kt + (scb[c] >> 1), lb);
    }
    __syncthreads();
#pragma unroll
    for (int ks = 0; ks < 2; ++ks) {
      bf16x8 af[4], bfr[4];
#pragma unroll
      for (int i = 0; i < 4; ++i) {
        int ra = wr * 64 + i * 16 + lq;
        int ca = (ks * 64 + lg * 16) ^ ((ra & 7) << 4);
        af[i] = *(const bf16x8*)((const char*)sA + ra * 128 + ca);
        int rb = wc * 64 + i * 16 + lq;
        int cb = (ks * 64 + lg * 16) ^ ((rb & 7) << 4);
        bfr[i] = *(const bf16x8*)((const char*)sB + rb * 128 + cb);
      }
#pragma unroll
      for (int i = 0; i < 4; ++i)
#pragma unroll
        for (int j = 0; j < 4; ++j)
          acc[i][j] = mfma16(af[i], bfr[j], acc[i][j]);
    }
    __syncthreads();
  }

  // C/D layout: col = lane&15, row = (lane>>4)*4 + r
  const int crow = m0 + wr * 64 + lg * 4;
  const int ccol = n0 + wc * 64 + lq;
#pragma unroll
  for (int j = 0; j < 4; ++j) {
    int col = ccol + j * 16;
    float bv = BIAS ? bias[col] : 0.0f;
#pragma unroll
    for (int i = 0; i < 4; ++i)
#pragma unroll
      for (int r = 0; r < 4; ++r) {
        size_t idx = (size_t)(crow + i * 16 + r) * N + col;
        float v = acc[i][j][r] + bv;
        if (BF16OUT) ((u16*)Cout)[idx] = f2b(v);
        else         ((float*)Cout)[idx] = v;
      }
  }
}

// ---------------- RoPE + reformat ----------------
// reference: out[2i] = -x[2i+1]*(sin+cos)[t,2i] ; out[2i+1] = x[2i]*(sin+cos)[t,2i+1]
// Y: (ROWS, NQKV) bf16. out: (BATCH, NHEADS, T, HD) bf16.
template<int NHEADS, int COLBASE>
__global__ void rope_kernel(const u16* __restrict__ Y, const float* __restrict__ cs,
                            u16* __restrict__ out)
{
  int pid = blockIdx.x * 256 + threadIdx.x;
  constexpr int TOTAL = ROWS * NHEADS * (HD / 2);
  if (pid >= TOTAL) return;
  int i  = pid & 63;                 // pair index (d = 2i)
  int hr = pid >> 6;
  int h  = hr & (NHEADS - 1);
  int r  = hr / NHEADS;              // 0..ROWS-1
  int t  = r & (T - 1);
  int b  = r >> 11;
  u32 y = *(const u32*)(Y + (size_t)r * NQKV + COLBASE + h * HD + 2 * i);
  float y0 = b2f((u16)(y & 0xffffu));
  float y1 = b2f((u16)(y >> 16));
  const float* cp = cs + t * HD + 2 * i;
  u32 o = (u32)f2b(-y1 * cp[0]) | ((u32)f2b(y0 * cp[1]) << 16);
  *(u32*)(out + (((size_t)(b * NHEADS + h) * T + t) * HD + 2 * i)) = o;
}

// V transpose: Vt[b][kh][d][t] = Y[b*T+t][2560 + kh*HD + d]
__global__ void vt_kernel(const u16* __restrict__ Y, u16* __restrict__ vt)
{
  int pid = blockIdx.x * 256 + threadIdx.x;
  constexpr int TOTAL = BATCH * KVH * HD * (T / 8);
  if (pid >= TOTAL) return;
  int tc = pid & 255;
  int d  = (pid >> 8) & 127;
  int kh = (pid >> 15) & 3;
  int b  = pid >> 17;
  const u16* src = Y + (size_t)(b * T + tc * 8) * NQKV + (DIM + KVH * HD) + kh * HD + d;
  u16x8 v;
#pragma unroll
  for (int j = 0; j < 8; ++j) v[j] = src[(size_t)j * NQKV];
  *(u16x8*)(vt + ((size_t)((b * KVH + kh) * HD + d) * T + tc * 8)) = v;
}

// ---------------- attention ----------------
// One wave per (b,h, 16-row q tile). Swapped orientation: S^T = K_tile · Q^T,
// softmax stats per q are lane-local after shfl_xor(16/32); PV as O^T = V^T · P^T.
__global__ __launch_bounds__(256) void attn_kernel(
    const u16* __restrict__ Qr, const u16* __restrict__ Kr,
    const u16* __restrict__ Vt, u16* __restrict__ Aout)
{
  constexpr int PSTR = 40;    // P row: 32 bf16 + pad (80B, 16B-aligned reads)
  constexpr int OSTR = 136;   // O row: 128 bf16 + pad (272B, 16B-aligned)
  __shared__ u16 ldsP[4][16 * PSTR];
  __shared__ u16 ldsO[4][16 * OSTR];
  const int w = threadIdx.x >> 6, lane = threadIdx.x & 63;
  const int task = blockIdx.x * 4 + w;
  const int qt = task & 127, bh = task >> 7;
  const int h = bh & (NH - 1), b = bh >> 4;
  const int kh = h >> 2;
  const int q0 = qt << 4;
  const int lq = lane & 15, lg = lane >> 4;

  // Q B-fragments: lane holds Q[q0+lq][ds*32 + lg*8 .. +7]
  const u16* Qp = Qr + ((size_t)bh * T + q0 + lq) * HD + lg * 8;
  bf16x8 qf[4];
#pragma unroll
  for (int ds = 0; ds < 4; ++ds) qf[ds] = *(const bf16x8*)(Qp + ds * 32);

  const u16* Kbase = Kr + (size_t)(b * KVH + kh) * T * HD;
  const u16* Vbase = Vt + (size_t)(b * KVH + kh) * HD * T;

  f32x4 accO[8] = {};                 // O^T: 8 d-blocks of 16, col = q = lq
  float m = -3.0e38f, lsum = 0.0f;
  const int nst = (q0 + 47) >> 5;     // 32-wide s tiles covering [0, q0+15]

  u16* pw = &ldsP[w][lq * PSTR];
  const bf16x8* prd = (const bf16x8*)&ldsP[w][lq * PSTR + lg * 8];
  const int qidx = q0 + lq;

  for (int st = 0; st < nst; ++st) {
    const int s0 = st << 5;
    f32x4 accS0 = {}, accS1 = {};
    const u16* Kp = Kbase + (size_t)(s0 + lq) * HD + lg * 8;
#pragma unroll
    for (int ds = 0; ds < 4; ++ds) {   // accumulate over d (K-loop recipe)
      bf16x8 kf0 = *(const bf16x8*)(Kp + ds * 32);
      bf16x8 kf1 = *(const bf16x8*)(Kp + 16 * HD + ds * 32);
      accS0 = mfma16(kf0, qf[ds], accS0);
      accS1 = mfma16(kf1, qf[ds], accS1);
    }
    // scale + causal mask; lane holds S^T[s0 + sb*16 + lg*4 + r][qidx]
    float sv[8];
#pragma unroll
    for (int r = 0; r < 4; ++r) {
      int si0 = s0 + lg * 4 + r;
      sv[r]     = (si0      <= qidx) ? accS0[r] * SCALE : -1.0e9f;
      sv[r + 4] = (si0 + 16 <= qidx) ? accS1[r] * SCALE : -1.0e9f;
    }
    float pm = sv[0];
#pragma unroll
    for (int r = 1; r < 8; ++r) pm = fmaxf(pm, sv[r]);
    pm = fmaxf(pm, __shfl_xor(pm, 16));
    pm = fmaxf(pm, __shfl_xor(pm, 32));
    float mnew = fmaxf(m, pm);
    float alpha = __expf(m - mnew);
    float p[8], ps = 0.0f;
#pragma unroll
    for (int r = 0; r < 8; ++r) { p[r] = __expf(sv[r] - mnew); ps += p[r]; }
    ps += __shfl_xor(ps, 16);
    ps += __shfl_xor(ps, 32);
    lsum = lsum * alpha + ps;
    m = mnew;
#pragma unroll
    for (int db = 0; db < 8; ++db) accO[db] *= alpha;

    // P^T -> LDS as [q][s] (bf16), then reread as PV B-fragment
    u16x4 pk0 = { f2b(p[0]), f2b(p[1]), f2b(p[2]), f2b(p[3]) };
    u16x4 pk1 = { f2b(p[4]), f2b(p[5]), f2b(p[6]), f2b(p[7]) };
    *(u16x4*)(pw + lg * 4)      = pk0;   // s = lg*4 + r
    *(u16x4*)(pw + 16 + lg * 4) = pk1;   // s = 16 + lg*4 + r
    asm volatile("" ::: "memory");       // keep write->read order (wave-synchronous DS)
    bf16x8 pf = *prd;                    // B[k=s=lg*8+j][col=q=lq]

    const u16* Vp = Vbase + (size_t)lq * T + s0 + lg * 8;
#pragma unroll
    for (int db = 0; db < 8; ++db) {     // A = V^T[d][s], d = db*16+lq
      bf16x8 vf = *(const bf16x8*)(Vp + (size_t)db * 16 * T);
      accO[db] = mfma16(vf, pf, accO[db]);
    }
    asm volatile("" ::: "memory");
  }

  // epilogue: O = accO/lsum, transpose via wave-private LDS, coalesced store
  float inv = 1.0f / lsum;
  u16* ow = &ldsO[w][0];
#pragma unroll
  for (int db = 0; db < 8; ++db) {
    u16x4 pk = { f2b(accO[db][0] * inv), f2b(accO[db][1] * inv),
                 f2b(accO[db][2] * inv), f2b(accO[db][3] * inv) };
    *(u16x4*)(ow + lq * OSTR + db * 16 + lg * 4) = pk;  // [q][d]
  }
  asm volatile("" ::: "memory");
  const int rq = lane >> 2, rc = lane & 3;
  const u16* orow = ow + rq * OSTR + rc * 32;
  u16* gout = Aout + ((size_t)b * T + q0 + rq) * DIM + h * HD + rc * 32;
#pragma unroll
  for (int i = 0; i < 4; ++i) {
    i32x4 v = *(const i32x4*)(orow + i * 8);
    *(i32x4*)(gout + i * 8) = v;
  }
}

// ---------------- launch ----------------
extern "C" void kernel_launch(void* const* d_in, const int* in_sizes, int n_in,
                              void* d_out, int out_size, void* d_ws, size_t ws_size,
                              hipStream_t stream) {
  const float* x    = (const float*)d_in[0];
  const float* cosp = (const float*)d_in[1];
  const float* sinp = (const float*)d_in[2];
  // d_in[3] = mask (causal, computed analytically)
  const float* Wq   = (const float*)d_in[4];
  const float* Wk   = (const float*)d_in[5];
  const float* Wv   = (const float*)d_in[6];
  const float* Wo   = (const float*)d_in[7];
  const float* bo   = (const float*)d_in[8];

  char* ws = (char*)d_ws;
  u16*   xb   = (u16*)(ws + 0);          // 16 MB  (ROWS*DIM bf16)   [reused as Qr]
  u16*   wqkv = (u16*)(ws + 16777216);   // 12 MB  (NQKV*DIM bf16)
  u16*   wout = (u16*)(ws + 29360128);   // 8 MB   (DIM*DIM bf16)
  float* cs   = (float*)(ws + 37748736); // 1 MB   (T*HD fp32)
  u16*   yqkv = (u16*)(ws + 38797312);   // 24 MB  (ROWS*NQKV bf16)  [reused as Aout]
  u16*   kr   = (u16*)(ws + 63963136);   // 4 MB
  u16*   vt   = (u16*)(ws + 68157440);   // 4 MB   (total 72,351,744 B)
  u16* qr   = xb;    // rope-Q output overwrites xb (xb consumed by GEMM1 before)
  u16* aout = yqkv;  // attention output overwrites yqkv (consumed by rope/vt before)

  cvt_bf16_kernel<<<ROWS * DIM / 4 / 256, 256, 0, stream>>>(x, xb, ROWS * DIM / 4);
  cvt_bf16_kernel<<<DIM * DIM / 4 / 256, 256, 0, stream>>>(Wq, wqkv, DIM * DIM / 4);
  cvt_bf16_kernel<<<512 * DIM / 4 / 256, 256, 0, stream>>>(Wk, wqkv + DIM * DIM, 512 * DIM / 4);
  cvt_bf16_kernel<<<512 * DIM / 4 / 256, 256, 0, stream>>>(Wv, wqkv + (size_t)(DIM + 512) * DIM, 512 * DIM / 4);
  cvt_bf16_kernel<<<DIM * DIM / 4 / 256, 256, 0, stream>>>(Wo, wout, DIM * DIM / 4);
  cs_kernel<<<T * HD / 256, 256, 0, stream>>>(cosp, sinp, cs, T * HD);

  gemm_bt_kernel<true, false><<<(ROWS / 128) * (NQKV / 128), 256, 0, stream>>>(
      xb, wqkv, yqkv, nullptr, ROWS, NQKV, DIM);

  rope_kernel<NH, 0><<<ROWS * NH * 64 / 256, 256, 0, stream>>>(yqkv, cs, qr);
  rope_kernel<KVH, DIM><<<ROWS * KVH * 64 / 256, 256, 0, stream>>>(yqkv, cs, kr);
  vt_kernel<<<BATCH * KVH * HD * (T / 8) / 256, 256, 0, stream>>>(yqkv, vt);

  attn_kernel<<<BATCH * NH * (T / 16) / 4, 256, 0, stream>>>(qr, kr, vt, aout);

  gemm_bt_kernel<false, true><<<(ROWS / 128) * (DIM / 128), 256, 0, stream>>>(
      aout, wout, d_out, bo, ROWS, DIM, DIM);
}

// Round 2
// 233.582 us; speedup vs baseline: 3.0191x; 3.0191x over previous
//
#include <hip/hip_runtime.h>

#define DEVI __device__ __forceinline__

typedef unsigned short u16;
typedef unsigned int u32;
typedef float f32x4 __attribute__((ext_vector_type(4)));
typedef __bf16 bf16x8 __attribute__((ext_vector_type(8)));
typedef unsigned short u16x4 __attribute__((ext_vector_type(4)));
typedef unsigned short u16x8 __attribute__((ext_vector_type(8)));
typedef int i32x4 __attribute__((ext_vector_type(4)));
typedef unsigned int u32x2 __attribute__((ext_vector_type(2)));

constexpr int BATCH = 2;
constexpr int T     = 2048;
constexpr int DIM   = 2048;
constexpr int NH    = 16;
constexpr int KVH   = 4;
constexpr int HD    = 128;
constexpr int NQKV  = DIM + 2 * KVH * HD;   // 3072 (q | k | v columns)
constexpr int ROWS  = BATCH * T;            // 4096
constexpr float SCALE = 0.08838834764831845f;           // 1/sqrt(HD)
constexpr float SC2   = 0.08838834764831845f * 1.4426950408889634f; // *log2(e)

DEVI u16 f2b(float f) {            // fp32 -> bf16 bits, round-nearest-even
  u32 u = __float_as_uint(f);
  return (u16)((u + 0x7fffu + ((u >> 16) & 1u)) >> 16);
}
DEVI float b2f(u16 u) { return __uint_as_float(((u32)u) << 16); }

DEVI u32 cvtpk(float lo, float hi) {   // 2xf32 -> packed bf16 pair
  u32 r;
  asm("v_cvt_pk_bf16_f32 %0, %1, %2" : "=v"(r) : "v"(lo), "v"(hi));
  return r;
}

DEVI f32x4 mfma16(bf16x8 a, bf16x8 b, f32x4 c) {
  return __builtin_amdgcn_mfma_f32_16x16x32_bf16(a, b, c, 0, 0, 0);
}
DEVI void gload16(const void* g, void* l) {  // async global->LDS, 16B/lane
  __builtin_amdgcn_global_load_lds((const __attribute__((address_space(1))) void*)g,
                                   (__attribute__((address_space(3))) void*)l, 16, 0, 0);
}

// ---------------- prep kernels ----------------
__global__ void cvt_bf16_kernel(const float* __restrict__ in, u16* __restrict__ out, int n4) {
  int i = blockIdx.x * 256 + threadIdx.x;
  if (i >= n4) return;
  float4 v = *((const float4*)in + i);
  u16x4 o = { f2b(v.x), f2b(v.y), f2b(v.z), f2b(v.w) };
  *((u16x4*)out + i) = o;
}

__global__ void cs_kernel(const float* __restrict__ c, const float* __restrict__ s,
                          float* __restrict__ cs, int n) {
  int i = blockIdx.x * 256 + threadIdx.x;
  if (i < n) cs[i] = c[i] + s[i];
}

// ---------------- GEMM: C = A @ W^T (+bias), A MxK, W NxK, bf16 in, fp32 acc --------
template<bool BF16OUT, bool BIAS>
__global__ __launch_bounds__(256) void gemm_bt_kernel(
    const u16* __restrict__ A, const u16* __restrict__ W,
    void* __restrict__ Cout, const float* __restrict__ bias,
    int M, int N, int K)
{
  constexpr int BK = 64;
  __shared__ u16 sA[128 * BK];
  __shared__ u16 sB[128 * BK];
  const int nbx = N >> 7;
  const int bx = blockIdx.x % nbx;
  const int by = blockIdx.x / nbx;
  const int m0 = by << 7, n0 = bx << 7;
  const int tid = threadIdx.x;
  const int w = tid >> 6, lane = tid & 63;
  const int wr = w >> 1, wc = w & 1;
  const int lq = lane & 15, lg = lane >> 4;

  f32x4 acc[4][4] = {};

  int srow[4], scb[4];
#pragma unroll
  for (int c = 0; c < 4; ++c) {
    int off = (w * 4 + c) * 1024 + lane * 16;       // byte offset in 16KB tile
    srow[c] = off >> 7;                             // 128B per row (64 bf16)
    scb[c]  = (off & 127) ^ ((srow[c] & 7) << 4);   // pre-swizzled source col-byte
  }

  for (int kt = 0; kt < K; kt += BK) {
#pragma unroll
    for (int c = 0; c < 4; ++c) {
      u16* la = sA + (w * 4 + c) * 512;             // wave-uniform LDS dest
      u16* lb = sB + (w * 4 + c) * 512;
      gload16(A + (size_t)(m0 + srow[c]) * K + kt + (scb[c] >> 1), la);
      gload16(W + (size_t)(n0 + srow[c]) * K + kt + (scb[c] >> 1), lb);
    }
    __syncthreads();
#pragma unroll
    for (int ks = 0; ks < 2; ++ks) {
      bf16x8 af[4], bfr[4];
#pragma unroll
      for (int i = 0; i < 4; ++i) {
        int ra = wr * 64 + i * 16 + lq;
        int ca = (ks * 64 + lg * 16) ^ ((ra & 7) << 4);
        af[i] = *(const bf16x8*)((const char*)sA + ra * 128 + ca);
        int rb = wc * 64 + i * 16 + lq;
        int cb = (ks * 64 + lg * 16) ^ ((rb & 7) << 4);
        bfr[i] = *(const bf16x8*)((const char*)sB + rb * 128 + cb);
      }
#pragma unroll
      for (int i = 0; i < 4; ++i)
#pragma unroll
        for (int j = 0; j < 4; ++j)
          acc[i][j] = mfma16(af[i], bfr[j], acc[i][j]);
    }
    __syncthreads();
  }

  // C/D layout: col = lane&15, row = (lane>>4)*4 + r
  const int crow = m0 + wr * 64 + lg * 4;
  const int ccol = n0 + wc * 64 + lq;
#pragma unroll
  for (int j = 0; j < 4; ++j) {
    int col = ccol + j * 16;
    float bv = BIAS ? bias[col] : 0.0f;
#pragma unroll
    for (int i = 0; i < 4; ++i)
#pragma unroll
      for (int r = 0; r < 4; ++r) {
        size_t idx = (size_t)(crow + i * 16 + r) * N + col;
        float v = acc[i][j][r] + bv;
        if (BF16OUT) ((u16*)Cout)[idx] = f2b(v);
        else         ((float*)Cout)[idx] = v;
      }
  }
}

// ---------------- RoPE + reformat ----------------
template<int NHEADS, int COLBASE>
__global__ void rope_kernel(const u16* __restrict__ Y, const float* __restrict__ cs,
                            u16* __restrict__ out)
{
  int pid = blockIdx.x * 256 + threadIdx.x;
  constexpr int TOTAL = ROWS * NHEADS * (HD / 2);
  if (pid >= TOTAL) return;
  int i  = pid & 63;                 // pair index (d = 2i)
  int hr = pid >> 6;
  int h  = hr & (NHEADS - 1);
  int r  = hr / NHEADS;              // 0..ROWS-1
  int t  = r & (T - 1);
  int b  = r >> 11;
  u32 y = *(const u32*)(Y + (size_t)r * NQKV + COLBASE + h * HD + 2 * i);
  float y0 = b2f((u16)(y & 0xffffu));
  float y1 = b2f((u16)(y >> 16));
  const float* cp = cs + t * HD + 2 * i;
  u32 o = (u32)f2b(-y1 * cp[0]) | ((u32)f2b(y0 * cp[1]) << 16);
  *(u32*)(out + (((size_t)(b * NHEADS + h) * T + t) * HD + 2 * i)) = o;
}

// V transpose: Vt[b][kh][d][t] = Y[b*T+t][2560 + kh*HD + d]
__global__ void vt_kernel(const u16* __restrict__ Y, u16* __restrict__ vt)
{
  int pid = blockIdx.x * 256 + threadIdx.x;
  constexpr int TOTAL = BATCH * KVH * HD * (T / 8);
  if (pid >= TOTAL) return;
  int tc = pid & 255;
  int d  = (pid >> 8) & 127;
  int kh = (pid >> 15) & 3;
  int b  = pid >> 17;
  const u16* src = Y + (size_t)(b * T + tc * 8) * NQKV + (DIM + KVH * HD) + kh * HD + d;
  u16x8 v;
#pragma unroll
  for (int j = 0; j < 8; ++j) v[j] = src[(size_t)j * NQKV];
  *(u16x8*)(vt + ((size_t)((b * KVH + kh) * HD + d) * T + tc * 8)) = v;
}

// ---------------- attention ----------------
// 4 waves/block, wave owns 32 q-rows (2 groups of 16); block = 128 q rows.
// KVBLK=64 K,V staged in LDS (global_load_lds, XOR-swizzled via pre-swizzled
// global source), double-buffered 2-phase pipeline. Swapped QK^T (S^T = K.Q^T),
// log2-domain online softmax with defer-max; P via per-wave LDS round-trip.
__global__ __launch_bounds__(256, 2) void attn_kernel(
    const u16* __restrict__ Qr, const u16* __restrict__ Kr,
    const u16* __restrict__ Vt, u16* __restrict__ Aout)
{
  __shared__ u16 ldsK[2][64 * 128];   // [s][d] rows 256B, swizzled
  __shared__ u16 ldsV[2][128 * 64];   // [d][s] rows 128B, swizzled
  __shared__ u16 ldsP[4][32 * 40];    // per-wave P relayout (32 q x 32 s + pad)

  const int tid = threadIdx.x;
  const int w = tid >> 6, lane = tid & 63;
  const int lq = lane & 15, lg = lane >> 4;

  // balanced mapping: second batch half reverses q-chunk order so co-resident
  // blocks (id, id+256) have complementary causal trip counts
  const int raw = blockIdx.x;
  const int bh = raw >> 4;                   // 0..31 = b*16 + h
  const int qcr = raw & 15;
  const int qc = (bh & 16) ? (15 - qcr) : qcr;
  const int b = bh >> 4, h = bh & 15, kh = h >> 2;
  const int qb = qc << 7;
  const int qw0 = qb + w * 32;
  const int nst = 2 * qc + 2;                // s-tiles of 64 covering [0, qb+128)

  // Q fragments: lane holds Q[qw0+qg*16+lq][ds*32 + lg*8 ..+7]
  bf16x8 qf[2][4];
  {
    const u16* Qp = Qr + ((size_t)bh * T + qw0 + lq) * HD + lg * 8;
#pragma unroll
    for (int qg = 0; qg < 2; ++qg)
#pragma unroll
      for (int ds = 0; ds < 4; ++ds)
        qf[qg][ds] = *(const bf16x8*)(Qp + qg * 16 * HD + ds * 32);
  }

  const u16* Kg = Kr + (size_t)(b * KVH + kh) * T * HD;
  const u16* Vg = Vt + (size_t)(b * KVH + kh) * HD * T;

  // cooperative staging offsets (elements); source pre-swizzled, LDS linear
  int kgo[4], klb[4], vgo[4], vlb[4];
  {
    const int vr = lane >> 3, vc = lane & 7;
#pragma unroll
    for (int i = 0; i < 4; ++i) {
      int krow = w * 16 + i * 4 + lg;                       // K tile row (s)
      kgo[i] = krow * HD + (((lq * 16) ^ ((krow & 7) << 4)) >> 1);
      klb[i] = (w * 16 + i * 4) * 128;
      int vrow = w * 32 + i * 8 + vr;                       // V tile row (d)
      vgo[i] = vrow * T + (((vc * 16) ^ ((vr & 7) << 4)) >> 1);
      vlb[i] = (w * 32 + i * 8) * 64;
    }
  }

  f32x4 accO[2][8] = {};
  float m[2]    = { -1e30f, -1e30f };
  float lsum[2] = { 0.f, 0.f };

  // prologue: stage tile 0 into buf 0
#pragma unroll
  for (int i = 0; i < 4; ++i) {
    gload16(Kg + kgo[i], &ldsK[0][klb[i]]);
    gload16(Vg + vgo[i], &ldsV[0][vlb[i]]);
  }
  __syncthreads();

  int cur = 0;
  for (int t = 0; t < nst; ++t) {
    if (t + 1 < nst) {                       // issue next-tile loads first
      const u16* Kt  = Kg + (size_t)(t + 1) * 64 * HD;
      const u16* Vts = Vg + (t + 1) * 64;
#pragma unroll
      for (int i = 0; i < 4; ++i) {
        gload16(Kt + kgo[i],  &ldsK[cur ^ 1][klb[i]]);
        gload16(Vts + vgo[i], &ldsV[cur ^ 1][vlb[i]]);
      }
    }
    const int s0 = t << 6;
    if (s0 <= qw0 + 31) {                    // causal: wave has live rows here
      const u16* Kb = ldsK[cur];
      const u16* Vb = ldsV[cur];
      // QK^T: aS[qg][si] = S^T[s=s0+si*16+lg*4+r][q=qw0+qg*16+lq] (scaled later)
      f32x4 aS[2][4] = {};
#pragma unroll
      for (int si = 0; si < 4; ++si) {
#pragma unroll
        for (int ds = 0; ds < 4; ++ds) {
          const u16* kp = Kb + (si * 16 + lq) * 128 +
                          (((ds * 64 + lg * 16) ^ ((lq & 7) << 4)) >> 1);
          bf16x8 kf = *(const bf16x8*)kp;
          aS[0][si] = mfma16(kf, qf[0][ds], aS[0][si]);
          aS[1][si] = mfma16(kf, qf[1][ds], aS[1][si]);
        }
      }
      // online softmax (log2 domain), defer-max
      float pp[2][16];
#pragma unroll
      for (int qg = 0; qg < 2; ++qg) {
        const int qidx = qw0 + qg * 16 + lq;
        float pm = -1e30f;
#pragma unroll
        for (int si = 0; si < 4; ++si)
#pragma unroll
          for (int r = 0; r < 4; ++r) {
            int s = s0 + si * 16 + lg * 4 + r;
            float v = (s <= qidx) ? aS[qg][si][r] * SC2 : -1e9f;
            pp[qg][si * 4 + r] = v;
            pm = fmaxf(pm, v);
          }
        pm = fmaxf(pm, __shfl_xor(pm, 16));
        pm = fmaxf(pm, __shfl_xor(pm, 32));
        if (!__all(pm <= m[qg] + 11.5f)) {   // rescale only on real max growth
          float mn = fmaxf(m[qg], pm);
          float al = __builtin_amdgcn_exp2f(m[qg] - mn);
          m[qg] = mn;
          lsum[qg] *= al;
#pragma unroll
          for (int db = 0; db < 8; ++db) accO[qg][db] *= al;
        }
        float ps = 0.f;
#pragma unroll
        for (int i2 = 0; i2 < 16; ++i2) {
          float e = __builtin_amdgcn_exp2f(pp[qg][i2] - m[qg]);
          pp[qg][i2] = e;
          ps += e;
        }
        ps += __shfl_xor(ps, 16);
        ps += __shfl_xor(ps, 32);
        lsum[qg] += ps;
      }
      // PV in two ks-halves: P^T->LDS [q][s_loc], reread as B-frag, V shared
#pragma unroll
      for (int ks = 0; ks < 2; ++ks) {
#pragma unroll
        for (int qg = 0; qg < 2; ++qg) {
          u16* pw = &ldsP[w][(qg * 16 + lq) * 40];
          u32x2 wa = { cvtpk(pp[qg][8 * ks + 0], pp[qg][8 * ks + 1]),
                       cvtpk(pp[qg][8 * ks + 2], pp[qg][8 * ks + 3]) };
          u32x2 wb = { cvtpk(pp[qg][8 * ks + 4], pp[qg][8 * ks + 5]),
                       cvtpk(pp[qg][8 * ks + 6], pp[qg][8 * ks + 7]) };
          *(u32x2*)(pw + lg * 4)      = wa;   // s_loc = lg*4 + r
          *(u32x2*)(pw + 16 + lg * 4) = wb;   // s_loc = 16 + lg*4 + r
        }
        asm volatile("" ::: "memory");
        bf16x8 pf0 = *(const bf16x8*)(&ldsP[w][lq * 40] + lg * 8);
        bf16x8 pf1 = *(const bf16x8*)(&ldsP[w][(16 + lq) * 40] + lg * 8);
        asm volatile("" ::: "memory");
#pragma unroll
        for (int db = 0; db < 8; ++db) {
          const u16* vp = Vb + (db * 16 + lq) * 64 +
                          (((ks * 64 + lg * 16) ^ ((lq & 7) << 4)) >> 1);
          bf16x8 vf = *(const bf16x8*)vp;
          accO[0][db] = mfma16(vf, pf0, accO[0][db]);
          accO[1][db] = mfma16(vf, pf1, accO[1][db]);
        }
      }
    }
    __syncthreads();                         // drains staged loads (vmcnt+lgkm)
    cur ^= 1;
  }

  // epilogue: O[q][d] direct store, lane holds O[q=qg*16+lq][d=db*16+lg*4+r]
  u16* Ab = Aout + ((size_t)b * T + qw0) * DIM + h * HD;
#pragma unroll
  for (int qg = 0; qg < 2; ++qg) {
    float inv = 1.0f / lsum[qg];
#pragma unroll
    for (int db = 0; db < 8; ++db) {
      u32x2 st = { cvtpk(accO[qg][db][0] * inv, accO[qg][db][1] * inv),
                   cvtpk(accO[qg][db][2] * inv, accO[qg][db][3] * inv) };
      *(u32x2*)(Ab + (size_t)(qg * 16 + lq) * DIM + db * 16 + lg * 4) = st;
    }
  }
}

// ---------------- launch ----------------
extern "C" void kernel_launch(void* const* d_in, const int* in_sizes, int n_in,
                              void* d_out, int out_size, void* d_ws, size_t ws_size,
                              hipStream_t stream) {
  const float* x    = (const float*)d_in[0];
  const float* cosp = (const float*)d_in[1];
  const float* sinp = (const float*)d_in[2];
  // d_in[3] = mask (causal, computed analytically)
  const float* Wq   = (const float*)d_in[4];
  const float* Wk   = (const float*)d_in[5];
  const float* Wv   = (const float*)d_in[6];
  const float* Wo   = (const float*)d_in[7];
  const float* bo   = (const float*)d_in[8];

  char* ws = (char*)d_ws;
  u16*   xb   = (u16*)(ws + 0);          // 16 MB  (ROWS*DIM bf16)   [reused as Qr]
  u16*   wqkv = (u16*)(ws + 16777216);   // 12 MB  (NQKV*DIM bf16)
  u16*   wout = (u16*)(ws + 29360128);   // 8 MB   (DIM*DIM bf16)
  float* cs   = (float*)(ws + 37748736); // 1 MB   (T*HD fp32)
  u16*   yqkv = (u16*)(ws + 38797312);   // 24 MB  (ROWS*NQKV bf16)  [reused as Aout]
  u16*   kr   = (u16*)(ws + 63963136);   // 4 MB
  u16*   vt   = (u16*)(ws + 68157440);   // 4 MB   (total 72,351,744 B)
  u16* qr   = xb;    // rope-Q output overwrites xb (xb consumed by GEMM1 before)
  u16* aout = yqkv;  // attention output overwrites yqkv (consumed by rope/vt before)

  cvt_bf16_kernel<<<ROWS * DIM / 4 / 256, 256, 0, stream>>>(x, xb, ROWS * DIM / 4);
  cvt_bf16_kernel<<<DIM * DIM / 4 / 256, 256, 0, stream>>>(Wq, wqkv, DIM * DIM / 4);
  cvt_bf16_kernel<<<512 * DIM / 4 / 256, 256, 0, stream>>>(Wk, wqkv + DIM * DIM, 512 * DIM / 4);
  cvt_bf16_kernel<<<512 * DIM / 4 / 256, 256, 0, stream>>>(Wv, wqkv + (size_t)(DIM + 512) * DIM, 512 * DIM / 4);
  cvt_bf16_kernel<<<DIM * DIM / 4 / 256, 256, 0, stream>>>(Wo, wout, DIM * DIM / 4);
  cs_kernel<<<T * HD / 256, 256, 0, stream>>>(cosp, sinp, cs, T * HD);

  gemm_bt_kernel<true, false><<<(ROWS / 128) * (NQKV / 128), 256, 0, stream>>>(
      xb, wqkv, yqkv, nullptr, ROWS, NQKV, DIM);

  rope_kernel<NH, 0><<<ROWS * NH * 64 / 256, 256, 0, stream>>>(yqkv, cs, qr);
  rope_kernel<KVH, DIM><<<ROWS * KVH * 64 / 256, 256, 0, stream>>>(yqkv, cs, kr);
  vt_kernel<<<BATCH * KVH * HD * (T / 8) / 256, 256, 0, stream>>>(yqkv, vt);

  attn_kernel<<<BATCH * NH * (T / 128), 256, 0, stream>>>(qr, kr, vt, aout);

  gemm_bt_kernel<false, true><<<(ROWS / 128) * (DIM / 128), 256, 0, stream>>>(
      aout, wout, d_out, bo, ROWS, DIM, DIM);
}

// Round 3
// 223.062 us; speedup vs baseline: 3.1614x; 1.0472x over previous
//
#include <hip/hip_runtime.h>
#include <type_traits>

#define DEVI __device__ __forceinline__

typedef unsigned short u16;
typedef unsigned int u32;
typedef float f32x4 __attribute__((ext_vector_type(4)));
typedef __bf16 bf16x8 __attribute__((ext_vector_type(8)));
typedef unsigned short u16x4 __attribute__((ext_vector_type(4)));
typedef unsigned short u16x8 __attribute__((ext_vector_type(8)));
typedef int i32x4 __attribute__((ext_vector_type(4)));
typedef unsigned int u32x2 __attribute__((ext_vector_type(2)));

constexpr int BATCH = 2;
constexpr int T     = 2048;
constexpr int DIM   = 2048;
constexpr int NH    = 16;
constexpr int KVH   = 4;
constexpr int HD    = 128;
constexpr int NQKV  = DIM + 2 * KVH * HD;   // 3072 (q | k | v columns)
constexpr int ROWS  = BATCH * T;            // 4096
constexpr float SCALE = 0.08838834764831845f;           // 1/sqrt(HD)
constexpr float SC2   = 0.08838834764831845f * 1.4426950408889634f; // *log2(e)

DEVI u16 f2b(float f) {            // fp32 -> bf16 bits, round-nearest-even
  u32 u = __float_as_uint(f);
  return (u16)((u + 0x7fffu + ((u >> 16) & 1u)) >> 16);
}
DEVI float b2f(u16 u) { return __uint_as_float(((u32)u) << 16); }

DEVI u32 cvtpk(float lo, float hi) {   // 2xf32 -> packed bf16 pair
  u32 r;
  asm("v_cvt_pk_bf16_f32 %0, %1, %2" : "=v"(r) : "v"(lo), "v"(hi));
  return r;
}

DEVI f32x4 mfma16(bf16x8 a, bf16x8 b, f32x4 c) {
  return __builtin_amdgcn_mfma_f32_16x16x32_bf16(a, b, c, 0, 0, 0);
}
DEVI void gload16(const void* g, void* l) {  // async global->LDS, 16B/lane
  __builtin_amdgcn_global_load_lds((const __attribute__((address_space(1))) void*)g,
                                   (__attribute__((address_space(3))) void*)l, 16, 0, 0);
}

// ---------------- prep kernels ----------------
__global__ void cvt_bf16_kernel(const float* __restrict__ in, u16* __restrict__ out, int n4) {
  int i = blockIdx.x * 256 + threadIdx.x;
  if (i >= n4) return;
  float4 v = *((const float4*)in + i);
  u16x4 o = { f2b(v.x), f2b(v.y), f2b(v.z), f2b(v.w) };
  *((u16x4*)out + i) = o;
}

__global__ void cs_kernel(const float* __restrict__ c, const float* __restrict__ s,
                          float* __restrict__ cs, int n) {
  int i = blockIdx.x * 256 + threadIdx.x;
  if (i < n) cs[i] = c[i] + s[i];
}

// ---------------- GEMM: C = A @ W^T (+bias), A MxK, W NxK, bf16 in, fp32 acc --------
template<bool BF16OUT, bool BIAS>
__global__ __launch_bounds__(256) void gemm_bt_kernel(
    const u16* __restrict__ A, const u16* __restrict__ W,
    void* __restrict__ Cout, const float* __restrict__ bias,
    int M, int N, int K)
{
  constexpr int BK = 64;
  __shared__ u16 sA[128 * BK];
  __shared__ u16 sB[128 * BK];
  const int nbx = N >> 7;
  const int bx = blockIdx.x % nbx;
  const int by = blockIdx.x / nbx;
  const int m0 = by << 7, n0 = bx << 7;
  const int tid = threadIdx.x;
  const int w = tid >> 6, lane = tid & 63;
  const int wr = w >> 1, wc = w & 1;
  const int lq = lane & 15, lg = lane >> 4;

  f32x4 acc[4][4] = {};

  int srow[4], scb[4];
#pragma unroll
  for (int c = 0; c < 4; ++c) {
    int off = (w * 4 + c) * 1024 + lane * 16;       // byte offset in 16KB tile
    srow[c] = off >> 7;                             // 128B per row (64 bf16)
    scb[c]  = (off & 127) ^ ((srow[c] & 7) << 4);   // pre-swizzled source col-byte
  }

  for (int kt = 0; kt < K; kt += BK) {
#pragma unroll
    for (int c = 0; c < 4; ++c) {
      u16* la = sA + (w * 4 + c) * 512;             // wave-uniform LDS dest
      u16* lb = sB + (w * 4 + c) * 512;
      gload16(A + (size_t)(m0 + srow[c]) * K + kt + (scb[c] >> 1), la);
      gload16(W + (size_t)(n0 + srow[c]) * K + kt + (scb[c] >> 1), lb);
    }
    __syncthreads();
#pragma unroll
    for (int ks = 0; ks < 2; ++ks) {
      bf16x8 af[4], bfr[4];
#pragma unroll
      for (int i = 0; i < 4; ++i) {
        int ra = wr * 64 + i * 16 + lq;
        int ca = (ks * 64 + lg * 16) ^ ((ra & 7) << 4);
        af[i] = *(const bf16x8*)((const char*)sA + ra * 128 + ca);
        int rb = wc * 64 + i * 16 + lq;
        int cb = (ks * 64 + lg * 16) ^ ((rb & 7) << 4);
        bfr[i] = *(const bf16x8*)((const char*)sB + rb * 128 + cb);
      }
#pragma unroll
      for (int i = 0; i < 4; ++i)
#pragma unroll
        for (int j = 0; j < 4; ++j)
          acc[i][j] = mfma16(af[i], bfr[j], acc[i][j]);
    }
    __syncthreads();
  }

  // C/D layout: col = lane&15, row = (lane>>4)*4 + r
  const int crow = m0 + wr * 64 + lg * 4;
  const int ccol = n0 + wc * 64 + lq;
#pragma unroll
  for (int j = 0; j < 4; ++j) {
    int col = ccol + j * 16;
    float bv = BIAS ? bias[col] : 0.0f;
#pragma unroll
    for (int i = 0; i < 4; ++i)
#pragma unroll
      for (int r = 0; r < 4; ++r) {
        size_t idx = (size_t)(crow + i * 16 + r) * N + col;
        float v = acc[i][j][r] + bv;
        if (BF16OUT) ((u16*)Cout)[idx] = f2b(v);
        else         ((float*)Cout)[idx] = v;
      }
  }
}

// ---------------- RoPE + reformat ----------------
// out[2i] = -x[2i+1]*cs[t,2i]*scale ; out[2i+1] = x[2i]*cs[t,2i+1]*scale
template<int NHEADS, int COLBASE>
__global__ void rope_kernel(const u16* __restrict__ Y, const float* __restrict__ cs,
                            u16* __restrict__ out, float scale)
{
  int pid = blockIdx.x * 256 + threadIdx.x;
  constexpr int TOTAL = ROWS * NHEADS * (HD / 2);
  if (pid >= TOTAL) return;
  int i  = pid & 63;                 // pair index (d = 2i)
  int hr = pid >> 6;
  int h  = hr & (NHEADS - 1);
  int r  = hr / NHEADS;              // 0..ROWS-1
  int t  = r & (T - 1);
  int b  = r >> 11;
  u32 y = *(const u32*)(Y + (size_t)r * NQKV + COLBASE + h * HD + 2 * i);
  float y0 = b2f((u16)(y & 0xffffu));
  float y1 = b2f((u16)(y >> 16));
  const float* cp = cs + t * HD + 2 * i;
  u32 o = (u32)f2b(-y1 * cp[0] * scale) | ((u32)f2b(y0 * cp[1] * scale) << 16);
  *(u32*)(out + (((size_t)(b * NHEADS + h) * T + t) * HD + 2 * i)) = o;
}

// V transpose via LDS tile: Vt[b][kh][d][t] = Y[b*T+t][2560 + kh*HD + d]
__global__ __launch_bounds__(256) void vt_kernel(const u16* __restrict__ Y, u16* __restrict__ vt)
{
  __shared__ u16 tile[64][136];            // 64 t-rows x 128 d (+8 pad)
  const int tid = threadIdx.x;
  const int tc = blockIdx.x & 31;          // 64-row t chunk
  const int kh = (blockIdx.x >> 5) & 3;
  const int b  = blockIdx.x >> 7;
  const u16* src = Y + (size_t)(b * T + tc * 64) * NQKV + (DIM + KVH * HD) + kh * HD;
#pragma unroll
  for (int pass = 0; pass < 4; ++pass) {
    int r = pass * 16 + (tid >> 4);
    int c = (tid & 15) * 8;
    *(u16x8*)&tile[r][c] = *(const u16x8*)(src + (size_t)r * NQKV + c);
  }
  __syncthreads();
  const int d = tid >> 1, th = tid & 1;
  u16* dst = vt + ((size_t)((b * KVH + kh) * HD + d) * T) + tc * 64 + th * 32;
#pragma unroll
  for (int j = 0; j < 4; ++j) {
    u16x8 v;
#pragma unroll
    for (int e = 0; e < 8; ++e) v[e] = tile[th * 32 + j * 8 + e][d];
    *(u16x8*)(dst + j * 8) = v;
  }
}

// ---------------- attention ----------------
// Fold-pair causal balancing: wave owns 16 q-rows from chunk p (qg0) and 16
// from chunk 31-p (qg1), same (b,kvh) -> shared K/V LDS. qg1 active all
// nst=32-p tiles; qg0 only t<=p. Uniform per-block work (33 tile-units).
// KVBLK=64 double-buffered via global_load_lds, XOR-swizzled. Swapped QK^T,
// log2-domain online softmax, defer-max, diagonal-only masking, setprio.
__global__ __launch_bounds__(256, 2) void attn_kernel(
    const u16* __restrict__ Qr, const u16* __restrict__ Kr,
    const u16* __restrict__ Vt, u16* __restrict__ Aout)
{
  __shared__ u16 ldsK[2][64 * 128];   // [s][d] rows 256B, swizzled
  __shared__ u16 ldsV[2][128 * 64];   // [d][s] rows 128B, swizzled
  __shared__ u16 ldsP[4][32 * 40];    // per-wave P relayout

  const int tid = threadIdx.x;
  const int w = tid >> 6, lane = tid & 63;
  const int lq = lane & 15, lg = lane >> 4;

  const int bh = blockIdx.x >> 4;            // 0..31 = b*16 + h
  const int p  = blockIdx.x & 15;            // pair index; p=0 longest, runs first
  const int b = bh >> 4, h = bh & 15, kh = h >> 2;
  const int qcA = p, qcB = 31 - p;
  const int rowA = qcA * 64 + w * 16;
  const int rowB = qcB * 64 + w * 16;
  const int nst = qcB + 1;                   // tiles of 64 s

  // Q fragments (Q pre-scaled by SC2 in rope)
  bf16x8 qf[2][4];
  {
    const u16* QpA = Qr + ((size_t)bh * T + rowA + lq) * HD + lg * 8;
    const u16* QpB = Qr + ((size_t)bh * T + rowB + lq) * HD + lg * 8;
#pragma unroll
    for (int ds = 0; ds < 4; ++ds) {
      qf[0][ds] = *(const bf16x8*)(QpA + ds * 32);
      qf[1][ds] = *(const bf16x8*)(QpB + ds * 32);
    }
  }

  const u16* Kg = Kr + (size_t)(b * KVH + kh) * T * HD;
  const u16* Vg = Vt + (size_t)(b * KVH + kh) * HD * T;

  // cooperative staging offsets; source pre-swizzled, LDS linear
  int kgo[4], klb[4], vgo[4], vlb[4];
  {
    const int vr = lane >> 3, vc = lane & 7;
#pragma unroll
    for (int i = 0; i < 4; ++i) {
      int krow = w * 16 + i * 4 + lg;
      kgo[i] = krow * HD + (((lq * 16) ^ ((krow & 7) << 4)) >> 1);
      klb[i] = (w * 16 + i * 4) * 128;
      int vrow = w * 32 + i * 8 + vr;
      vgo[i] = vrow * T + (((vc * 16) ^ ((vr & 7) << 4)) >> 1);
      vlb[i] = (w * 32 + i * 8) * 64;
    }
  }

  f32x4 accO[2][8] = {};
  float m[2]    = { -1e30f, -1e30f };
  float lsum[2] = { 0.f, 0.f };

#pragma unroll
  for (int i = 0; i < 4; ++i) {
    gload16(Kg + kgo[i], &ldsK[0][klb[i]]);
    gload16(Vg + vgo[i], &ldsV[0][vlb[i]]);
  }
  __syncthreads();

  int cur = 0;
  for (int t = 0; t < nst; ++t) {
    if (t + 1 < nst) {
      const u16* Kt  = Kg + (size_t)(t + 1) * 64 * HD;
      const u16* Vts = Vg + (t + 1) * 64;
#pragma unroll
      for (int i = 0; i < 4; ++i) {
        gload16(Kt + kgo[i],  &ldsK[cur ^ 1][klb[i]]);
        gload16(Vts + vgo[i], &ldsV[cur ^ 1][vlb[i]]);
      }
    }
    const int s0 = t << 6;
    const u16* Kb = ldsK[cur];
    const u16* Vb = ldsV[cur];

    auto softmax_qg = [&](f32x4 (&s4)[4], int qidx, bool diag, float& mm, float& ls,
                          f32x4 (&aO)[8], float (&pp)[16]) {
      float pm = -1e30f;
      if (diag) {
#pragma unroll
        for (int si = 0; si < 4; ++si)
#pragma unroll
          for (int r = 0; r < 4; ++r) {
            int s = s0 + si * 16 + lg * 4 + r;
            float v = (s <= qidx) ? s4[si][r] : -1e9f;
            pp[si * 4 + r] = v; pm = fmaxf(pm, v);
          }
      } else {
#pragma unroll
        for (int si = 0; si < 4; ++si)
#pragma unroll
          for (int r = 0; r < 4; ++r) {
            float v = s4[si][r];
            pp[si * 4 + r] = v; pm = fmaxf(pm, v);
          }
      }
      pm = fmaxf(pm, __shfl_xor(pm, 16));
      pm = fmaxf(pm, __shfl_xor(pm, 32));
      if (!__all(pm <= mm + 11.5f)) {
        float mn = fmaxf(mm, pm);
        float al = __builtin_amdgcn_exp2f(mm - mn);
        mm = mn; ls *= al;
#pragma unroll
        for (int db = 0; db < 8; ++db) aO[db] *= al;
      }
      float ps = 0.f;
#pragma unroll
      for (int i2 = 0; i2 < 16; ++i2) {
        float e = __builtin_amdgcn_exp2f(pp[i2] - mm);
        pp[i2] = e; ps += e;
      }
      ps += __shfl_xor(ps, 16);
      ps += __shfl_xor(ps, 32);
      ls += ps;
    };

    auto tile_body = [&](auto hasA_c) {
      constexpr bool HASA = decltype(hasA_c)::value;
      f32x4 aS[2][4] = {};
      __builtin_amdgcn_s_setprio(1);
#pragma unroll
      for (int si = 0; si < 4; ++si)
#pragma unroll
        for (int ds = 0; ds < 4; ++ds) {
          const u16* kp = Kb + (si * 16 + lq) * 128 +
                          (((ds * 64 + lg * 16) ^ ((lq & 7) << 4)) >> 1);
          bf16x8 kf = *(const bf16x8*)kp;
          if constexpr (HASA) aS[0][si] = mfma16(kf, qf[0][ds], aS[0][si]);
          aS[1][si] = mfma16(kf, qf[1][ds], aS[1][si]);
        }
      __builtin_amdgcn_s_setprio(0);

      float pp[2][16];
      if constexpr (HASA)
        softmax_qg(aS[0], rowA + lq, t == qcA, m[0], lsum[0], accO[0], pp[0]);
      softmax_qg(aS[1], rowB + lq, t == qcB, m[1], lsum[1], accO[1], pp[1]);

#pragma unroll
      for (int ks = 0; ks < 2; ++ks) {
        if constexpr (HASA) {
          u16* pw = &ldsP[w][lq * 40];
          u32x2 wa = { cvtpk(pp[0][8 * ks + 0], pp[0][8 * ks + 1]),
                       cvtpk(pp[0][8 * ks + 2], pp[0][8 * ks + 3]) };
          u32x2 wb = { cvtpk(pp[0][8 * ks + 4], pp[0][8 * ks + 5]),
                       cvtpk(pp[0][8 * ks + 6], pp[0][8 * ks + 7]) };
          *(u32x2*)(pw + lg * 4)      = wa;
          *(u32x2*)(pw + 16 + lg * 4) = wb;
        }
        {
          u16* pw = &ldsP[w][(16 + lq) * 40];
          u32x2 wa = { cvtpk(pp[1][8 * ks + 0], pp[1][8 * ks + 1]),
                       cvtpk(pp[1][8 * ks + 2], pp[1][8 * ks + 3]) };
          u32x2 wb = { cvtpk(pp[1][8 * ks + 4], pp[1][8 * ks + 5]),
                       cvtpk(pp[1][8 * ks + 6], pp[1][8 * ks + 7]) };
          *(u32x2*)(pw + lg * 4)      = wa;
          *(u32x2*)(pw + 16 + lg * 4) = wb;
        }
        asm volatile("" ::: "memory");
        bf16x8 pf0, pf1;
        if constexpr (HASA) pf0 = *(const bf16x8*)(&ldsP[w][lq * 40] + lg * 8);
        pf1 = *(const bf16x8*)(&ldsP[w][(16 + lq) * 40] + lg * 8);
        asm volatile("" ::: "memory");
        __builtin_amdgcn_s_setprio(1);
#pragma unroll
        for (int db = 0; db < 8; ++db) {
          const u16* vp = Vb + (db * 16 + lq) * 64 +
                          (((ks * 64 + lg * 16) ^ ((lq & 7) << 4)) >> 1);
          bf16x8 vf = *(const bf16x8*)vp;
          if constexpr (HASA) accO[0][db] = mfma16(vf, pf0, accO[0][db]);
          accO[1][db] = mfma16(vf, pf1, accO[1][db]);
        }
        __builtin_amdgcn_s_setprio(0);
      }
    };

    if (t <= qcA) tile_body(std::integral_constant<bool, true>{});
    else          tile_body(std::integral_constant<bool, false>{});

    __syncthreads();                         // drains staged loads
    cur ^= 1;
  }

  // epilogue: lane holds O[q = rowX+lq][d = db*16+lg*4+r]
#pragma unroll
  for (int qg = 0; qg < 2; ++qg) {
    const int rowX = qg ? rowB : rowA;
    float inv = 1.0f / (qg ? lsum[1] : lsum[0]);
    u16* Ab = Aout + ((size_t)b * T + rowX + lq) * DIM + h * HD;
#pragma unroll
    for (int db = 0; db < 8; ++db) {
      f32x4 a = qg ? accO[1][db] : accO[0][db];
      u32x2 st = { cvtpk(a[0] * inv, a[1] * inv),
                   cvtpk(a[2] * inv, a[3] * inv) };
      *(u32x2*)(Ab + db * 16 + lg * 4) = st;
    }
  }
}

// ---------------- launch ----------------
extern "C" void kernel_launch(void* const* d_in, const int* in_sizes, int n_in,
                              void* d_out, int out_size, void* d_ws, size_t ws_size,
                              hipStream_t stream) {
  const float* x    = (const float*)d_in[0];
  const float* cosp = (const float*)d_in[1];
  const float* sinp = (const float*)d_in[2];
  // d_in[3] = mask (causal, computed analytically)
  const float* Wq   = (const float*)d_in[4];
  const float* Wk   = (const float*)d_in[5];
  const float* Wv   = (const float*)d_in[6];
  const float* Wo   = (const float*)d_in[7];
  const float* bo   = (const float*)d_in[8];

  char* ws = (char*)d_ws;
  u16*   xb   = (u16*)(ws + 0);          // 16 MB  (ROWS*DIM bf16)   [reused as Qr]
  u16*   wqkv = (u16*)(ws + 16777216);   // 12 MB  (NQKV*DIM bf16)
  u16*   wout = (u16*)(ws + 29360128);   // 8 MB   (DIM*DIM bf16)
  float* cs   = (float*)(ws + 37748736); // 1 MB   (T*HD fp32)
  u16*   yqkv = (u16*)(ws + 38797312);   // 24 MB  (ROWS*NQKV bf16)  [reused as Aout]
  u16*   kr   = (u16*)(ws + 63963136);   // 4 MB
  u16*   vt   = (u16*)(ws + 68157440);   // 4 MB   (total 72,351,744 B)
  u16* qr   = xb;    // rope-Q output overwrites xb (xb consumed by GEMM1 before)
  u16* aout = yqkv;  // attention output overwrites yqkv (consumed by rope/vt before)

  cvt_bf16_kernel<<<ROWS * DIM / 4 / 256, 256, 0, stream>>>(x, xb, ROWS * DIM / 4);
  cvt_bf16_kernel<<<DIM * DIM / 4 / 256, 256, 0, stream>>>(Wq, wqkv, DIM * DIM / 4);
  cvt_bf16_kernel<<<512 * DIM / 4 / 256, 256, 0, stream>>>(Wk, wqkv + DIM * DIM, 512 * DIM / 4);
  cvt_bf16_kernel<<<512 * DIM / 4 / 256, 256, 0, stream>>>(Wv, wqkv + (size_t)(DIM + 512) * DIM, 512 * DIM / 4);
  cvt_bf16_kernel<<<DIM * DIM / 4 / 256, 256, 0, stream>>>(Wo, wout, DIM * DIM / 4);
  cs_kernel<<<T * HD / 256, 256, 0, stream>>>(cosp, sinp, cs, T * HD);

  gemm_bt_kernel<true, false><<<(ROWS / 128) * (NQKV / 128), 256, 0, stream>>>(
      xb, wqkv, yqkv, nullptr, ROWS, NQKV, DIM);

  rope_kernel<NH, 0><<<ROWS * NH * 64 / 256, 256, 0, stream>>>(yqkv, cs, qr, SC2);
  rope_kernel<KVH, DIM><<<ROWS * KVH * 64 / 256, 256, 0, stream>>>(yqkv, cs, kr, 1.0f);
  vt_kernel<<<BATCH * KVH * (T / 64), 256, 0, stream>>>(yqkv, vt);

  attn_kernel<<<BATCH * NH * 16, 256, 0, stream>>>(qr, kr, vt, aout);

  gemm_bt_kernel<false, true><<<(ROWS / 128) * (DIM / 128), 256, 0, stream>>>(
      aout, wout, d_out, bo, ROWS, DIM, DIM);
}